// Round 6
// baseline (322.352 us; speedup 1.0000x reference)
//
#include <hip/hip_runtime.h>
#include <hip/hip_bf16.h>

#define NN 4096
#define CAP 128   // max nnz per row tracked (binomial mean 41, sd 6.4)
#define KS 8      // k-splits for P-GEMM
#define PGB 512   // pgemm virtual blocks at the head of phase 1

typedef __attribute__((ext_vector_type(8))) short bf16x8;
typedef __attribute__((ext_vector_type(4))) float f32x4;

__device__ __forceinline__ float lrelu(float v) { return v >= 0.f ? v : 0.2f * v; }

// fp32 -> bf16 bits, round-to-nearest-even (inputs are finite)
__device__ __forceinline__ ushort f2bu(float f) {
    unsigned u = __float_as_uint(f);
    return (ushort)((u + 0x7FFFu + ((u >> 16) & 1u)) >> 16);
}

// ---------------------------------------------------------------------------
// K1: xwA1=x@W1[0], xwB1=x@W1[1], xwA2=x@W2[0], xwB2=x@W2[1], v0=x@W0,
//     a/b attention vectors, Bt = (x@W0)^T as bf16 for the P-GEMM.
//     Also zeroes the grid-barrier counters for k_mega (kernel-boundary
//     ordering on the stream guarantees visibility).
// ---------------------------------------------------------------------------
__global__ __launch_bounds__(256) void k_prep(
    const float* __restrict__ x,
    const float* __restrict__ W1, const float* __restrict__ W2,
    const float* __restrict__ W0,
    const float* __restrict__ att1, const float* __restrict__ att2,
    float* __restrict__ xwA1, float* __restrict__ xwB1,
    float* __restrict__ xwA2, float* __restrict__ xwB2,
    float* __restrict__ a1, float* __restrict__ b1,
    float* __restrict__ a2, float* __restrict__ b2,
    __hip_bfloat16* __restrict__ Bt, unsigned* __restrict__ ctr)
{
    if (blockIdx.x == 0 && threadIdx.x < 2) ctr[threadIdx.x] = 0u;

    __shared__ float wl[5120];   // W1(2048) W2(2048) W0(1024)
    __shared__ float xs[256];    // 8 rows x 32
    const int t = threadIdx.x;
    for (int i = t; i < 2048; i += 256) { wl[i] = W1[i]; wl[2048 + i] = W2[i]; }
    for (int i = t; i < 1024; i += 256) wl[4096 + i] = W0[i];
    const int rowBase = blockIdx.x * 8;
    xs[t] = x[rowBase * 32 + t];
    __syncthreads();

    const int o = t & 31, r = t >> 5;
    const int row = rowBase + r;
    const float* xr = &xs[r * 32];
    float vA1 = 0.f, vB1 = 0.f, vA2 = 0.f, vB2 = 0.f, v0 = 0.f;
#pragma unroll
    for (int f = 0; f < 32; ++f) {
        const float xv = xr[f];
        vA1 += xv * wl[f * 32 + o];
        vB1 += xv * wl[1024 + f * 32 + o];
        vA2 += xv * wl[2048 + f * 32 + o];
        vB2 += xv * wl[3072 + f * 32 + o];
        v0  += xv * wl[4096 + f * 32 + o];
    }
    xwA1[row * 32 + o] = vA1;
    xwB1[row * 32 + o] = vB1;
    xwA2[row * 32 + o] = vA2;
    xwB2[row * 32 + o] = vB2;
    ((ushort*)Bt)[(size_t)o * NN + row] = f2bu(v0);

    float pa1 = vA1 * att1[o]      + vB1 * att1[32 + o];
    float pb1 = vA1 * att1[64 + o] + vB1 * att1[96 + o];
    float pa2 = vA2 * att2[o]      + vB2 * att2[32 + o];
    float pb2 = vA2 * att2[64 + o] + vB2 * att2[96 + o];
#pragma unroll
    for (int m = 1; m <= 16; m <<= 1) {
        pa1 += __shfl_xor(pa1, m); pb1 += __shfl_xor(pb1, m);
        pa2 += __shfl_xor(pa2, m); pb2 += __shfl_xor(pb2, m);
    }
    if (o == 0) { a1[row] = pa1; b1[row] = pb1; a2[row] = pa2; b2[row] = pb2; }
}

// ---------------------------------------------------------------------------
// K2 (k_mega): persistent kernel, B co-resident blocks (B from occupancy
// query, <= 2048).
//   phase 1 (grid-stride over PGB+2*NN virtuals):
//     vb <  PGB         : pgemm body (wave-autonomous MFMA, verified r4/r5)
//     vb >= PGB         : scan6 body (verified r4/r5), br/row from vb
//   in-kernel grid barrier (device-scope atomics + release/acquire fences)
//   phase 2 (grid-stride over NN/2 virtuals): accum, wave per (row,branch),
//     csrv read direct from L2 (entries read once; no LDS staging needed).
// Eliminates the fused->accum dispatch boundary and its tail; one profile
// line = exact GPU time of everything after prep.
// ---------------------------------------------------------------------------
__global__ __launch_bounds__(256) void k_mega(
    const float* __restrict__ Ld, const float* __restrict__ Lu,
    const float* __restrict__ xwB1, const float* __restrict__ xwB2,
    const float* __restrict__ xwA1, const float* __restrict__ xwA2,
    const float* __restrict__ a1, const float* __restrict__ b1,
    const float* __restrict__ a2, const float* __restrict__ b2,
    int2* __restrict__ csrv, int* __restrict__ cntArr,
    float* __restrict__ u1, float* __restrict__ u2,
    const float* __restrict__ P, const ushort* __restrict__ Bt,
    float* __restrict__ partial, float* __restrict__ outp,
    unsigned* __restrict__ ctr, int B)
{
    __shared__ union {
        struct {
            int   sidx[CAP];
            float sval[CAP];
            int   wcnt[16];
            float red[256];
            float rpart[8];
        } s;
        float sacc[4][32];
    } sh;

    const int bid = blockIdx.x;
    const int t = threadIdx.x;
    const int lane = t & 63, w = t >> 6;

    // ================= phase 1: pgemm + scan =================
    for (int vb = bid; vb < PGB + 2 * NN; vb += B) {
        if (vb < PGB) {
            // ---------------- pgemm body ----------------
            const int gw = vb * 4 + w;             // 0..2047
            const int mt = gw & 255;               // m-tile (16 rows)
            const int ks = gw >> 8;                // k-split 0..7
            const int m0 = mt * 16;
            const int r  = lane & 15;              // A row / B col within tile
            const int kq = lane >> 4;              // 8-k subchunk 0..3

            const float*  pa  = P  + (size_t)(m0 + r) * NN + ks * 512 + kq * 8;
            const ushort* pb0 = Bt + (size_t)r        * NN + ks * 512 + kq * 8;
            const ushort* pb1 = Bt + (size_t)(16 + r) * NN + ks * 512 + kq * 8;

            f32x4 acc0 = {0.f, 0.f, 0.f, 0.f};
            f32x4 acc1 = {0.f, 0.f, 0.f, 0.f};

#pragma unroll 4
            for (int kk = 0; kk < 16; ++kk) {
                const float4 a0  = *(const float4*)(pa + kk * 32);
                const float4 a1v = *(const float4*)(pa + kk * 32 + 4);
                const bf16x8 b0  = *(const bf16x8*)(pb0 + kk * 32);
                const bf16x8 b1v = *(const bf16x8*)(pb1 + kk * 32);
                bf16x8 a;
                a[0] = (short)f2bu(a0.x);  a[1] = (short)f2bu(a0.y);
                a[2] = (short)f2bu(a0.z);  a[3] = (short)f2bu(a0.w);
                a[4] = (short)f2bu(a1v.x); a[5] = (short)f2bu(a1v.y);
                a[6] = (short)f2bu(a1v.z); a[7] = (short)f2bu(a1v.w);
                acc0 = __builtin_amdgcn_mfma_f32_16x16x32_bf16(a, b0, acc0, 0, 0, 0);
                acc1 = __builtin_amdgcn_mfma_f32_16x16x32_bf16(a, b1v, acc1, 0, 0, 0);
            }

            // C/D layout: col = lane&15 (=r), row = (lane>>4)*4 + rr
            float* out = partial + ((size_t)ks * NN + m0 + kq * 4) * 32;
#pragma unroll
            for (int rr = 0; rr < 4; ++rr) {
                out[rr * 32 + r]      = acc0[rr];
                out[rr * 32 + 16 + r] = acc1[rr];
            }
            continue;
        }

        // ---------------- scan body ----------------
        const int sb  = vb - PGB;             // 0..8191
        const int br  = sb >> 12;             // 0..1
        const int row = sb & (NN - 1);
        const float* L   = br ? Lu : Ld;
        const float* xwB = br ? xwB2 : xwB1;
        const float* xwA = br ? xwA2 : xwA1;
        const float* aA  = br ? a2 : a1;
        const float* bA  = br ? b2 : b1;
        int2* csrB = csrv + ((size_t)br * NN + row) * CAP;
        float* u   = br ? u2 : u1;

        // stream the row: 4 float4 in flight
        const float4* L4 = (const float4*)(L + (size_t)row * NN);
        float4 v[4];
#pragma unroll
        for (int it = 0; it < 4; ++it) v[it] = L4[it * 256 + t];

        const unsigned long long lt = (1ull << lane) - 1ull;

        // phase a: ballot ONCE, cache masks (wave-uniform -> SGPRs)
        unsigned long long M0[4], M1[4], M2[4], M3[4];
        int tots[4];
#pragma unroll
        for (int it = 0; it < 4; ++it) {
            M0[it] = __ballot(v[it].x != 0.f);
            M1[it] = __ballot(v[it].y != 0.f);
            M2[it] = __ballot(v[it].z != 0.f);
            M3[it] = __ballot(v[it].w != 0.f);
            tots[it] = __popcll(M0[it]) + __popcll(M1[it]) + __popcll(M2[it]) + __popcll(M3[it]);
        }
        if (lane == 0) {
            int4 tv; tv.x = tots[0]; tv.y = tots[1]; tv.z = tots[2]; tv.w = tots[3];
            *(int4*)&sh.s.wcnt[w * 4] = tv;
        }
        __syncthreads();

        // phase b: prefix over 16 counts, compact into LDS using cached masks
        const int4 ca = *(const int4*)&sh.s.wcnt[0];
        const int4 cb = *(const int4*)&sh.s.wcnt[4];
        const int4 cc = *(const int4*)&sh.s.wcnt[8];
        const int4 cd = *(const int4*)&sh.s.wcnt[12];
        const int cs[16] = {ca.x, ca.y, ca.z, ca.w, cb.x, cb.y, cb.z, cb.w,
                            cc.x, cc.y, cc.z, cc.w, cd.x, cd.y, cd.z, cd.w};
        int total = 0;
#pragma unroll
        for (int k2 = 0; k2 < 16; ++k2) total += cs[k2];
        int base = 0;
#pragma unroll
        for (int k2 = 0; k2 < 16; ++k2) base += (k2 < (w << 2)) ? cs[k2] : 0;

        const int cnt  = min(total, CAP);
        const int cp16 = min((cnt + 15) & ~15, CAP);

#pragma unroll
        for (int it = 0; it < 4; ++it) {
            const float vx = v[it].x, vy = v[it].y, vz = v[it].z, vw = v[it].w;
            const int p0 = __popcll(M0[it]), p1 = __popcll(M1[it]), p2 = __popcll(M2[it]);
            const int c0 = (it * 256 + t) * 4;
            int s;
            s = base + __popcll(M0[it] & lt);
            if (vx != 0.f && s < CAP) { sh.s.sidx[s] = c0;     sh.s.sval[s] = vx; }
            s = base + p0 + __popcll(M1[it] & lt);
            if (vy != 0.f && s < CAP) { sh.s.sidx[s] = c0 + 1; sh.s.sval[s] = vy; }
            s = base + p0 + p1 + __popcll(M2[it] & lt);
            if (vz != 0.f && s < CAP) { sh.s.sidx[s] = c0 + 2; sh.s.sval[s] = vz; }
            s = base + p0 + p1 + p2 + __popcll(M3[it] & lt);
            if (vw != 0.f && s < CAP) { sh.s.sidx[s] = c0 + 3; sh.s.sval[s] = vw; }
            base += p0 + p1 + p2 + __popcll(M3[it]);
        }
        // sentinel padding: safe idx 0, value 0
        if (t >= cnt && t < cp16) { sh.s.sidx[t] = 0; sh.s.sval[t] = 0.f; }
        __syncthreads();

        // --- softmax over the list: thread t handles slot t ---
        const float ai = aA[row];
        const int myidx = (t < cp16) ? sh.s.sidx[t] : 0;
        const float e = (t < cnt) ? lrelu(ai + bA[myidx]) : -1e30f;
        float m = e;
#pragma unroll
        for (int mm = 1; mm <= 32; mm <<= 1) m = fmaxf(m, __shfl_xor(m, mm));
        if (lane == 0) sh.s.rpart[w] = m;
        __syncthreads();
        m = fmaxf(fmaxf(sh.s.rpart[0], sh.s.rpart[1]), fmaxf(sh.s.rpart[2], sh.s.rpart[3]));
        const float wgt = (t < cnt) ? __expf(e - m) : 0.f;
        float ss = wgt;
#pragma unroll
        for (int mm = 1; mm <= 32; mm <<= 1) ss += __shfl_xor(ss, mm);
        if (lane == 0) sh.s.rpart[4 + w] = ss;
        __syncthreads();
        const float ssum = sh.s.rpart[4] + sh.s.rpart[5] + sh.s.rpart[6] + sh.s.rpart[7];
        const float inv = (cnt > 0) ? 1.f / ssum : 0.f;
        if (t < cp16) { int2 eo; eo.x = myidx; eo.y = __float_as_int(wgt * inv); csrB[t] = eo; }
        if (t == 0) cntArr[br * NN + row] = cnt;

        // --- fused y-gather (raw values still in LDS) ---
        const int o = t & 31, g = t >> 5;
        float acc = 0.f;
        const int nPair = cp16 >> 4;     // 16 slots per batch: 2 per group
        if (nPair > 0) {
            float vA0 = sh.s.sval[g],      vA1 = sh.s.sval[g + 8];
            float xA0 = xwB[(size_t)sh.s.sidx[g] * 32 + o];
            float xA1 = xwB[(size_t)sh.s.sidx[g + 8] * 32 + o];
            for (int j = 1; j < nPair; ++j) {
                const int sB = g + 16 * j;
                const float vB0 = sh.s.sval[sB],  vB1 = sh.s.sval[sB + 8];
                const float xB0 = xwB[(size_t)sh.s.sidx[sB] * 32 + o];
                const float xB1 = xwB[(size_t)sh.s.sidx[sB + 8] * 32 + o];
                acc += vA0 * xA0 + vA1 * xA1;
                vA0 = vB0; xA0 = xB0; vA1 = vB1; xA1 = xB1;
            }
            acc += vA0 * xA0 + vA1 * xA1;
        }
        sh.s.red[t] = acc;
        __syncthreads();
        if (t < 32) {
            float tot2 = 0.f;
#pragma unroll
            for (int g2 = 0; g2 < 8; ++g2) tot2 += sh.s.red[g2 * 32 + t];
            u[(size_t)row * 32 + t] = tot2 + xwA[(size_t)row * 32 + t];
        }
        // no extra barrier needed: next virtual's pre-barrier LDS writes
        // (wcnt) don't alias red/sval/sidx, and its compact writes are
        // ordered by its own first __syncthreads.
    }

    // ================= grid barrier =================
    __syncthreads();
    if (t == 0) {
        __threadfence();                               // release (device scope)
        atomicAdd(&ctr[0], 1u);
        while (__hip_atomic_load(&ctr[0], __ATOMIC_ACQUIRE,
                                 __HIP_MEMORY_SCOPE_AGENT) < (unsigned)B)
            __builtin_amdgcn_s_sleep(8);
    }
    __syncthreads();

    // ================= phase 2: accum =================
    // wave per (row, branch): virtual vb covers rows vb*2, vb*2+1.
    for (int vb = bid; vb < NN / 2; vb += B) {
        const int row = vb * 2 + (w >> 1);
        const int br  = w & 1;
        const float* U = br ? u2 : u1;
        const int cnt = cntArr[br * NN + row];
        const int cp  = min((cnt + 15) & ~15, CAP);
        const int2* ci = csrv + ((size_t)br * NN + row) * CAP;
        const int o = lane & 31, g = lane >> 5;
        float acc = 0.f;
        const int nb = cp >> 3;
        for (int j = 0; j < nb; ++j) {
            float wv[4], uv[4];
#pragma unroll
            for (int q = 0; q < 4; ++q) {
                const int2 e = ci[8 * j + 2 * q + g];
                wv[q] = __int_as_float(e.y);
                uv[q] = U[(size_t)e.x * 32 + o];
            }
#pragma unroll
            for (int q = 0; q < 4; ++q) acc += wv[q] * uv[q];
        }
        acc += __shfl_xor(acc, 32);
        if (lane < 32) sh.sacc[w][o] = acc;
        __syncthreads();
        if ((w & 1) == 0 && lane < 32) {
            float total = sh.sacc[w][o] + sh.sacc[w + 1][o];
#pragma unroll
            for (int p = 0; p < KS; ++p)
                total += partial[(size_t)p * NN * 32 + (size_t)row * 32 + o];
            outp[(size_t)row * 32 + o] = total;
        }
        __syncthreads();
    }
}

extern "C" void kernel_launch(void* const* d_in, const int* in_sizes, int n_in,
                              void* d_out, int out_size, void* d_ws, size_t ws_size,
                              hipStream_t stream) {
    (void)in_sizes; (void)n_in; (void)out_size; (void)ws_size;
    const float* x    = (const float*)d_in[0];
    const float* Ld   = (const float*)d_in[1];
    const float* Lu   = (const float*)d_in[2];
    const float* P    = (const float*)d_in[3];
    const float* W1   = (const float*)d_in[4];
    const float* W2   = (const float*)d_in[5];
    const float* W0   = (const float*)d_in[6];
    const float* att1 = (const float*)d_in[7];
    const float* att2 = (const float*)d_in[8];

    float* ws = (float*)d_ws;
    float* xwA1 = ws;                 // 131072 each
    float* xwB1 = ws + 131072;
    float* xwA2 = ws + 262144;
    float* xwB2 = ws + 393216;
    float* u1   = ws + 524288;        // xwA + L@xwB (fused)
    float* u2   = ws + 655360;
    float* a1   = ws + 786432;        // 4096 each
    float* b1   = ws + 790528;
    float* a2   = ws + 794624;
    float* b2   = ws + 798720;
    float* partial = ws + 802816;           // KS*131072 floats = 4 MB
    __hip_bfloat16* Bt = (__hip_bfloat16*)(ws + 1851392);   // 131072 bf16
    int2* csrv = (int2*)(ws + 1916928);     // 2*4096*128 int2 = 8 MB
    int*  cnt  = (int*)(ws + 4014080);      // 8192 ints
    unsigned* ctr = (unsigned*)(ws + 4022272);  // 2 barrier counters

    // co-residency: size the persistent grid by the occupancy query (host-side
    // pure query, graph-capture safe); cached across launches.
    static int occ_cached = -1;
    if (occ_cached < 0) {
        int occ = 0;
        if (hipOccupancyMaxActiveBlocksPerMultiprocessor(&occ, k_mega, 256, 0)
                != hipSuccess || occ <= 0)
            occ = 4;   // conservative fallback: 4 blocks/CU always fits
        occ_cached = occ;
    }
    int B = occ_cached * 256;
    if (B > 2048) B = 2048;

    k_prep<<<512, 256, 0, stream>>>(x, W1, W2, W0, att1, att2,
                                    xwA1, xwB1, xwA2, xwB2, a1, b1, a2, b2,
                                    (__hip_bfloat16*)Bt, ctr);
    k_mega<<<B, 256, 0, stream>>>(Ld, Lu, xwB1, xwB2, xwA1, xwA2,
                                  a1, b1, a2, b2, csrv, cnt, u1, u2,
                                  P, (const ushort*)Bt, partial,
                                  (float*)d_out, ctr, B);
}

// Round 7
// 221.916 us; speedup vs baseline: 1.4526x; 1.4526x over previous
//
#include <hip/hip_runtime.h>
#include <hip/hip_bf16.h>

#define NN 4096
#define CAP 128   // max nnz per row tracked (binomial mean 41, sd 6.4)
#define KS 8      // k-splits for P-GEMM
#define PGB 1024  // pgemm blocks (128-thr, 2 wave-tiles each) at grid head

typedef __attribute__((ext_vector_type(8))) short bf16x8;
typedef __attribute__((ext_vector_type(4))) float f32x4;

__device__ __forceinline__ float lrelu(float v) { return v >= 0.f ? v : 0.2f * v; }

// fp32 -> bf16 bits, round-to-nearest-even (inputs are finite)
__device__ __forceinline__ ushort f2bu(float f) {
    unsigned u = __float_as_uint(f);
    return (ushort)((u + 0x7FFFu + ((u >> 16) & 1u)) >> 16);
}

// ---------------------------------------------------------------------------
// K1: xwA1=x@W1[0], xwB1=x@W1[1], xwA2=x@W2[0], xwB2=x@W2[1], v0=x@W0,
//     a/b attention vectors, Bt = (x@W0)^T as bf16 for the P-GEMM.
// ---------------------------------------------------------------------------
__global__ __launch_bounds__(256) void k_prep(
    const float* __restrict__ x,
    const float* __restrict__ W1, const float* __restrict__ W2,
    const float* __restrict__ W0,
    const float* __restrict__ att1, const float* __restrict__ att2,
    float* __restrict__ xwA1, float* __restrict__ xwB1,
    float* __restrict__ xwA2, float* __restrict__ xwB2,
    float* __restrict__ a1, float* __restrict__ b1,
    float* __restrict__ a2, float* __restrict__ b2,
    __hip_bfloat16* __restrict__ Bt)
{
    __shared__ float wl[5120];   // W1(2048) W2(2048) W0(1024)
    __shared__ float xs[256];    // 8 rows x 32
    const int t = threadIdx.x;
    for (int i = t; i < 2048; i += 256) { wl[i] = W1[i]; wl[2048 + i] = W2[i]; }
    for (int i = t; i < 1024; i += 256) wl[4096 + i] = W0[i];
    const int rowBase = blockIdx.x * 8;
    xs[t] = x[rowBase * 32 + t];
    __syncthreads();

    const int o = t & 31, r = t >> 5;
    const int row = rowBase + r;
    const float* xr = &xs[r * 32];
    float vA1 = 0.f, vB1 = 0.f, vA2 = 0.f, vB2 = 0.f, v0 = 0.f;
#pragma unroll
    for (int f = 0; f < 32; ++f) {
        const float xv = xr[f];
        vA1 += xv * wl[f * 32 + o];
        vB1 += xv * wl[1024 + f * 32 + o];
        vA2 += xv * wl[2048 + f * 32 + o];
        vB2 += xv * wl[3072 + f * 32 + o];
        v0  += xv * wl[4096 + f * 32 + o];
    }
    xwA1[row * 32 + o] = vA1;
    xwB1[row * 32 + o] = vB1;
    xwA2[row * 32 + o] = vA2;
    xwB2[row * 32 + o] = vB2;
    ((ushort*)Bt)[(size_t)o * NN + row] = f2bu(v0);

    float pa1 = vA1 * att1[o]      + vB1 * att1[32 + o];
    float pb1 = vA1 * att1[64 + o] + vB1 * att1[96 + o];
    float pa2 = vA2 * att2[o]      + vB2 * att2[32 + o];
    float pb2 = vA2 * att2[64 + o] + vB2 * att2[96 + o];
#pragma unroll
    for (int m = 1; m <= 16; m <<= 1) {
        pa1 += __shfl_xor(pa1, m); pb1 += __shfl_xor(pb1, m);
        pa2 += __shfl_xor(pa2, m); pb2 += __shfl_xor(pb2, m);
    }
    if (o == 0) { a1[row] = pa1; b1[row] = pb1; a2[row] = pa2; b2[row] = pb2; }
}

// ---------------------------------------------------------------------------
// K2 (k_fused): heterogeneous dispatch, 128-thread blocks.
//   blocks [0, PGB)        : pgemm body, 2 wave-tiles per block (per-wave
//                            MFMA, no LDS, no barriers) -- scheduled first.
//   blocks [PGB, PGB+2*NN) : scan body, ONE row per block at 128 threads:
//                            16 blocks/CU (2x rows in flight vs 256-thr),
//                            8 float4/lane outstanding (2x bytes in flight),
//                            2-wave barriers, per-wave running compaction
//                            base (single cross-wave scalar exchange).
// List order differs from the 256-thr version; all consumers (softmax,
// csrv->accum, y-gather) are order-invariant.
// ---------------------------------------------------------------------------
__global__ __launch_bounds__(128) void k_fused(
    const float* __restrict__ Ld, const float* __restrict__ Lu,
    const float* __restrict__ xwB1, const float* __restrict__ xwB2,
    const float* __restrict__ xwA1, const float* __restrict__ xwA2,
    const float* __restrict__ a1, const float* __restrict__ b1,
    const float* __restrict__ a2, const float* __restrict__ b2,
    int2* __restrict__ csrv, int* __restrict__ cntArr,
    float* __restrict__ u1, float* __restrict__ u2,
    const float* __restrict__ P, const ushort* __restrict__ Bt,
    float* __restrict__ partial)
{
    __shared__ int   sidx[CAP];
    __shared__ float sval[CAP];
    __shared__ float red[128];
    __shared__ int   wtot[2];
    __shared__ float rpart[4];

    const int bid = blockIdx.x;
    const int t = threadIdx.x;
    const int lane = t & 63, w = t >> 6;      // w in {0,1}

    if (bid < PGB) {
        // ---------------- pgemm body (per-wave, verified r4/r5) ----------
        const int gw = bid * 2 + w;            // 0..2047
        const int mt = gw & 255;               // m-tile (16 rows)
        const int ks = gw >> 8;                // k-split 0..7
        const int m0 = mt * 16;
        const int r  = lane & 15;              // A row / B col within tile
        const int kq = lane >> 4;              // 8-k subchunk 0..3

        const float*  pa  = P  + (size_t)(m0 + r) * NN + ks * 512 + kq * 8;
        const ushort* pb0 = Bt + (size_t)r        * NN + ks * 512 + kq * 8;
        const ushort* pb1 = Bt + (size_t)(16 + r) * NN + ks * 512 + kq * 8;

        f32x4 acc0 = {0.f, 0.f, 0.f, 0.f};
        f32x4 acc1 = {0.f, 0.f, 0.f, 0.f};

#pragma unroll 4
        for (int kk = 0; kk < 16; ++kk) {
            const float4 a0  = *(const float4*)(pa + kk * 32);
            const float4 a1v = *(const float4*)(pa + kk * 32 + 4);
            const bf16x8 b0  = *(const bf16x8*)(pb0 + kk * 32);
            const bf16x8 b1v = *(const bf16x8*)(pb1 + kk * 32);
            bf16x8 a;
            a[0] = (short)f2bu(a0.x);  a[1] = (short)f2bu(a0.y);
            a[2] = (short)f2bu(a0.z);  a[3] = (short)f2bu(a0.w);
            a[4] = (short)f2bu(a1v.x); a[5] = (short)f2bu(a1v.y);
            a[6] = (short)f2bu(a1v.z); a[7] = (short)f2bu(a1v.w);
            acc0 = __builtin_amdgcn_mfma_f32_16x16x32_bf16(a, b0, acc0, 0, 0, 0);
            acc1 = __builtin_amdgcn_mfma_f32_16x16x32_bf16(a, b1v, acc1, 0, 0, 0);
        }

        // C/D layout: col = lane&15 (=r), row = (lane>>4)*4 + rr
        float* out = partial + ((size_t)ks * NN + m0 + kq * 4) * 32;
#pragma unroll
        for (int rr = 0; rr < 4; ++rr) {
            out[rr * 32 + r]      = acc0[rr];
            out[rr * 32 + 16 + r] = acc1[rr];
        }
        return;
    }

    // ---------------- scan body: one row, 128 threads ----------------
    const int sb  = bid - PGB;            // 0..8191
    const int br  = sb >> 12;             // 0..1
    const int row = sb & (NN - 1);
    const float* L   = br ? Lu : Ld;
    const float* xwB = br ? xwB2 : xwB1;
    const float* xwA = br ? xwA2 : xwA1;
    const float* aA  = br ? a2 : a1;
    const float* bA  = br ? b2 : b1;
    int2* csrB = csrv + ((size_t)br * NN + row) * CAP;
    float* u   = br ? u2 : u1;

    // issue the whole row: 8 float4 per lane, all in flight
    const float4* L4 = (const float4*)(L + (size_t)row * NN);
    float4 v[8];
#pragma unroll
    for (int j = 0; j < 8; ++j) v[j] = L4[j * 128 + t];

    const unsigned long long lt = (1ull << lane) - 1ull;

    // pass 1: per-wave nonzero total
    int tw = 0;
#pragma unroll
    for (int j = 0; j < 8; ++j) {
        tw += __popcll(__ballot(v[j].x != 0.f));
        tw += __popcll(__ballot(v[j].y != 0.f));
        tw += __popcll(__ballot(v[j].z != 0.f));
        tw += __popcll(__ballot(v[j].w != 0.f));
    }
    if (lane == 0) wtot[w] = tw;
    __syncthreads();

    const int t0 = wtot[0];
    const int total = t0 + wtot[1];
    const int cnt  = min(total, CAP);
    const int cp16 = min((cnt + 15) & ~15, CAP);
    int base = w ? t0 : 0;                 // per-wave running base

    // pass 2: re-ballot and compact (order-invariant consumers)
#pragma unroll
    for (int j = 0; j < 8; ++j) {
        const float vx = v[j].x, vy = v[j].y, vz = v[j].z, vw = v[j].w;
        const unsigned long long m0 = __ballot(vx != 0.f);
        const unsigned long long m1 = __ballot(vy != 0.f);
        const unsigned long long m2 = __ballot(vz != 0.f);
        const unsigned long long m3 = __ballot(vw != 0.f);
        const int p0 = __popcll(m0), p1 = __popcll(m1), p2 = __popcll(m2);
        const int c0 = (j * 128 + t) * 4;
        int s;
        s = base + __popcll(m0 & lt);
        if (vx != 0.f && s < CAP) { sidx[s] = c0;     sval[s] = vx; }
        s = base + p0 + __popcll(m1 & lt);
        if (vy != 0.f && s < CAP) { sidx[s] = c0 + 1; sval[s] = vy; }
        s = base + p0 + p1 + __popcll(m2 & lt);
        if (vz != 0.f && s < CAP) { sidx[s] = c0 + 2; sval[s] = vz; }
        s = base + p0 + p1 + p2 + __popcll(m3 & lt);
        if (vw != 0.f && s < CAP) { sidx[s] = c0 + 3; sval[s] = vw; }
        base += p0 + p1 + p2 + __popcll(m3);
    }
    // sentinel padding: safe idx 0, value 0
    if (t >= cnt && t < cp16) { sidx[t] = 0; sval[t] = 0.f; }
    __syncthreads();

    // --- softmax over the list: thread t handles slot t (cp16 <= 128) ---
    const float ai = aA[row];
    const int myidx = (t < cp16) ? sidx[t] : 0;
    const float e = (t < cnt) ? lrelu(ai + bA[myidx]) : -1e30f;
    float m = e;
#pragma unroll
    for (int mm = 1; mm <= 32; mm <<= 1) m = fmaxf(m, __shfl_xor(m, mm));
    if (lane == 0) rpart[w] = m;
    __syncthreads();
    m = fmaxf(rpart[0], rpart[1]);
    const float wgt = (t < cnt) ? __expf(e - m) : 0.f;
    float ss = wgt;
#pragma unroll
    for (int mm = 1; mm <= 32; mm <<= 1) ss += __shfl_xor(ss, mm);
    if (lane == 0) rpart[2 + w] = ss;
    __syncthreads();
    const float ssum = rpart[2] + rpart[3];
    const float inv = (cnt > 0) ? 1.f / ssum : 0.f;
    if (t < cp16) { int2 eo; eo.x = myidx; eo.y = __float_as_int(wgt * inv); csrB[t] = eo; }
    if (t == 0) cntArr[br * NN + row] = cnt;

    // --- fused y-gather: 4 groups of 32, 4 slots per group per 16-batch ---
    const int o = t & 31, g = t >> 5;      // g in 0..3
    float acc = 0.f;
    for (int s0 = 0; s0 < cp16; s0 += 16) {
        float vv[4], uu[4];
#pragma unroll
        for (int q = 0; q < 4; ++q) {
            const int sl = s0 + 4 * q + g;
            const int ix = sidx[sl];
            vv[q] = sval[sl];
            uu[q] = xwB[(size_t)ix * 32 + o];
        }
#pragma unroll
        for (int q = 0; q < 4; ++q) acc += vv[q] * uu[q];
    }
    red[t] = acc;
    __syncthreads();
    if (t < 32) {
        const float tot2 = red[t] + red[32 + t] + red[64 + t] + red[96 + t];
        u[(size_t)row * 32 + t] = tot2 + xwA[(size_t)row * 32 + t];
    }
}

// ---------------------------------------------------------------------------
// K3 (k_accum): wave per row. Pure weighted gather of U for both branches
// (weights pre-normalized in csrv), fold in KS partials, write d_out.
// ---------------------------------------------------------------------------
__global__ __launch_bounds__(256) void k_accum(
    const int2* __restrict__ csrv, const int* __restrict__ cntArr,
    const float* __restrict__ u1, const float* __restrict__ u2,
    const float* __restrict__ partial, float* __restrict__ outp)
{
    __shared__ int2 sle[4][2 * CAP];
    const int w = threadIdx.x >> 6, lane = threadIdx.x & 63;
    const int row = blockIdx.x * 4 + w;
    const int o = lane & 31, g = lane >> 5;
    int2* se = sle[w];
    float total = 0.f;

    int cp[2];
#pragma unroll
    for (int br = 0; br < 2; ++br) {
        const int cnt = cntArr[br * NN + row];
        cp[br] = min((cnt + 15) & ~15, CAP);
        const int2* ci = csrv + ((size_t)br * NN + row) * CAP;
        if (lane < cp[br])      se[br * CAP + lane]      = ci[lane];
        if (lane + 64 < cp[br]) se[br * CAP + lane + 64] = ci[lane + 64];
    }
    // wave-private LDS segment; same-wave ordering

#pragma unroll
    for (int br = 0; br < 2; ++br) {
        const float* U = br ? u2 : u1;
        float acc = 0.f;
        const int nb = cp[br] >> 3;
        for (int j = 0; j < nb; ++j) {
            float wv[4], uv[4];
#pragma unroll
            for (int q = 0; q < 4; ++q) {
                const int2 e = se[br * CAP + 8 * j + 2 * q + g];
                wv[q] = __int_as_float(e.y);
                uv[q] = U[(size_t)e.x * 32 + o];
            }
#pragma unroll
            for (int q = 0; q < 4; ++q) acc += wv[q] * uv[q];
        }
        acc += __shfl_xor(acc, 32);
        total += acc;
    }

    if (lane < 32) {
#pragma unroll
        for (int p = 0; p < KS; ++p)
            total += partial[(size_t)p * NN * 32 + (size_t)row * 32 + o];
        outp[(size_t)row * 32 + o] = total;
    }
}

extern "C" void kernel_launch(void* const* d_in, const int* in_sizes, int n_in,
                              void* d_out, int out_size, void* d_ws, size_t ws_size,
                              hipStream_t stream) {
    (void)in_sizes; (void)n_in; (void)out_size; (void)ws_size;
    const float* x    = (const float*)d_in[0];
    const float* Ld   = (const float*)d_in[1];
    const float* Lu   = (const float*)d_in[2];
    const float* P    = (const float*)d_in[3];
    const float* W1   = (const float*)d_in[4];
    const float* W2   = (const float*)d_in[5];
    const float* W0   = (const float*)d_in[6];
    const float* att1 = (const float*)d_in[7];
    const float* att2 = (const float*)d_in[8];

    float* ws = (float*)d_ws;
    float* xwA1 = ws;                 // 131072 each
    float* xwB1 = ws + 131072;
    float* xwA2 = ws + 262144;
    float* xwB2 = ws + 393216;
    float* u1   = ws + 524288;        // xwA + L@xwB (fused)
    float* u2   = ws + 655360;
    float* a1   = ws + 786432;        // 4096 each
    float* b1   = ws + 790528;
    float* a2   = ws + 794624;
    float* b2   = ws + 798720;
    float* partial = ws + 802816;           // KS*131072 floats = 4 MB
    __hip_bfloat16* Bt = (__hip_bfloat16*)(ws + 1851392);   // 131072 bf16
    int2* csrv = (int2*)(ws + 1916928);     // 2*4096*128 int2 = 8 MB
    int*  cnt  = (int*)(ws + 4014080);      // 8192 ints

    k_prep<<<512, 256, 0, stream>>>(x, W1, W2, W0, att1, att2,
                                    xwA1, xwB1, xwA2, xwB2, a1, b1, a2, b2, Bt);
    k_fused<<<PGB + 2 * NN, 128, 0, stream>>>(Ld, Lu, xwB1, xwB2, xwA1, xwA2,
                                              a1, b1, a2, b2, csrv, cnt, u1, u2,
                                              P, (const ushort*)Bt, partial);
    k_accum<<<NN / 4, 256, 0, stream>>>(csrv, cnt, u1, u2, partial,
                                        (float*)d_out);
}